// Round 3
// baseline (1844.520 us; speedup 1.0000x reference)
//
#include <hip/hip_runtime.h>
#include <math.h>

#define SDIM 2048
#define BATCH 1024
#define NITER 16
#define LM 40   // Lanczos steps

typedef unsigned short ushort_t;
typedef __attribute__((ext_vector_type(8))) short bf16x8;
typedef __attribute__((ext_vector_type(4))) float f32x4;

#define MFMA(a,b,c) __builtin_amdgcn_mfma_f32_16x16x32_bf16((a),(b),(c),0,0,0)

__device__ __forceinline__ float softt(float v, float th){
  return copysignf(fmaxf(fabsf(v) - th, 0.0f), v);
}

__device__ __forceinline__ float bf2f(ushort_t h){
  return __uint_as_float(((unsigned)h) << 16);
}

// RTNE float -> bf16 hi + bf16 lo split
__device__ __forceinline__ void split2(float x, ushort_t* h, ushort_t* l){
  unsigned u = __float_as_uint(x);
  unsigned hh = (u + 0x7FFFu + ((u >> 16) & 1u)) >> 16;
  float hf = __uint_as_float(hh << 16);
  float r = x - hf;                       // exact
  unsigned v = __float_as_uint(r);
  unsigned ll = (v + 0x7FFFu + ((v >> 16) & 1u)) >> 16;
  *h = (ushort_t)hh; *l = (ushort_t)ll;
}

// async 16B global -> LDS
__device__ __forceinline__ void cp16(const ushort_t* g, ushort_t* l){
  __builtin_amdgcn_global_load_lds(
      (const __attribute__((address_space(1))) unsigned int*)g,
      (__attribute__((address_space(3))) unsigned int*)l, 16, 0, 0);
}

// ---------------- MFMA GEMM core v3: BM x BN = 128x64 tile, 4 waves each
// computing 64x32. LDS-read traffic factor wn/BN + wm/BM = 3/64 (vs 1/16 for
// the old 64x64 core) -- the GEMMs are LDS-BW-bound, so this is the lever.
// Double-buffered LDS (2 x (2*BM+2*BN)*64*2B = 96KB, dynamic), ONE barrier
// per K-step: the syncthreads' vmcnt(0) drain waits only on stage loads
// issued a full K-step earlier (covered by ds_read+MFMA of that step).
// Stage for step k+1 is issued immediately AFTER the barrier -> all waves
// provably finished reading that buffer (it was last read at step k-1, and
// its consumers' lgkmcnt waits completed before they reached barrier k).
// K/64 must be EVEN so the last step reads buf1 (epilogue tile reuses buf0).
template<int BM, int BN>
__device__ __forceinline__ void gemm_core2(ushort_t* __restrict__ sm,
    const ushort_t* __restrict__ Ah, const ushort_t* __restrict__ Al,
    const ushort_t* __restrict__ Bh, const ushort_t* __restrict__ Bl,
    int m0, int n0, int K, f32x4 acc[4][2])
{
  constexpr int BK   = 64;
  constexpr int ABUF = BM * BK;            // ushorts per A array
  constexpr int BBUF = BN * BK;
  constexpr int BUFSZ = 2*ABUF + 2*BBUF;   // one stage buffer
  constexpr int ARND = BM / 32;            // 32 rows staged per 256-thread round
  constexpr int BRND = BN / 32;
  const int tid = threadIdx.x;
  const int rr = tid >> 3;                 // 0..31 (row within round)
  const int kp = (tid & 7) ^ (rr & 7);     // source-side XOR pre-swizzle

  const ushort_t* pAh[ARND]; const ushort_t* pAl[ARND];
  const ushort_t* pBh[BRND]; const ushort_t* pBl[BRND];
  #pragma unroll
  for (int r = 0; r < ARND; r++){
    pAh[r] = Ah + (size_t)(m0 + rr + r*32) * K + kp*8;
    pAl[r] = Al + (size_t)(m0 + rr + r*32) * K + kp*8;
  }
  #pragma unroll
  for (int r = 0; r < BRND; r++){
    pBh[r] = Bh + (size_t)(n0 + rr + r*32) * K + kp*8;
    pBl[r] = Bl + (size_t)(n0 + rr + r*32) * K + kp*8;
  }

  const int lane = tid & 63, wv = tid >> 6;
  const int wr = (wv >> 1) * 64, wc = (wv & 1) * 32;   // wave sub-tile origin
  const int mm = lane & 15, quad = lane >> 4;
  int oa[4][2], ob[2][2];
  #pragma unroll
  for (int t = 0; t < 4; t++){
    const int r = wr + t*16 + mm;
    #pragma unroll
    for (int u = 0; u < 2; u++)
      oa[t][u] = r*BK + (((u*4 + quad) ^ (r & 7)) << 3);
  }
  #pragma unroll
  for (int s = 0; s < 2; s++){
    const int r = wc + s*16 + mm;
    #pragma unroll
    for (int u = 0; u < 2; u++)
      ob[s][u] = r*BK + (((u*4 + quad) ^ (r & 7)) << 3);
  }

  const int nk = K / BK;   // even by construction (K=2048)
  // prologue: stage K-step 0 into buf0
  #pragma unroll
  for (int r = 0; r < ARND; r++){
    cp16(pAh[r], &sm[(tid + r*256)*8]);
    cp16(pAl[r], &sm[ABUF + (tid + r*256)*8]);
  }
  #pragma unroll
  for (int r = 0; r < BRND; r++){
    cp16(pBh[r], &sm[2*ABUF + (tid + r*256)*8]);
    cp16(pBl[r], &sm[2*ABUF + BBUF + (tid + r*256)*8]);
  }

  for (int kt = 0; kt < nk; kt++){
    const int cur = kt & 1;
    __syncthreads();   // vmcnt(0) drain of buf[cur] loads (issued 1 step ago) + handoff
    if (kt + 1 < nk){
      ushort_t* d = sm + (cur ^ 1) * BUFSZ;
      const int ko = (kt + 1) * BK;
      #pragma unroll
      for (int r = 0; r < ARND; r++){
        cp16(pAh[r] + ko, &d[(tid + r*256)*8]);
        cp16(pAl[r] + ko, &d[ABUF + (tid + r*256)*8]);
      }
      #pragma unroll
      for (int r = 0; r < BRND; r++){
        cp16(pBh[r] + ko, &d[2*ABUF + (tid + r*256)*8]);
        cp16(pBl[r] + ko, &d[2*ABUF + BBUF + (tid + r*256)*8]);
      }
    }
    const ushort_t* sA  = sm + cur * BUFSZ;
    const ushort_t* sAl = sA + ABUF;
    const ushort_t* sB  = sA + 2*ABUF;
    const ushort_t* sBl = sA + 2*ABUF + BBUF;
    #pragma unroll
    for (int u = 0; u < 2; u++){
      bf16x8 ah[4], al8[4], bh[2], bl8[2];
      #pragma unroll
      for (int t = 0; t < 4; t++){
        ah[t]  = *(const bf16x8*)&sA [oa[t][u]];
        al8[t] = *(const bf16x8*)&sAl[oa[t][u]];
      }
      #pragma unroll
      for (int s = 0; s < 2; s++){
        bh[s]  = *(const bf16x8*)&sB [ob[s][u]];
        bl8[s] = *(const bf16x8*)&sBl[ob[s][u]];
      }
      #pragma unroll
      for (int t = 0; t < 4; t++)
        #pragma unroll
        for (int s = 0; s < 2; s++){
          acc[t][s] = MFMA(ah[t],  bh[s],  acc[t][s]);
          acc[t][s] = MFMA(ah[t],  bl8[s], acc[t][s]);
          acc[t][s] = MFMA(al8[t], bh[s],  acc[t][s]);
        }
    }
  }
}

// Dump acc to LDS fp32 tile 128x64 (stride 65, conflict-free). Tile occupies
// the first 33KB of buf0; the last K-step read buf1 (nk even), so no hazard,
// and all waves passed the final barrier before any buf0 read completed late.
__device__ __forceinline__ void acc_to_tile2(ushort_t* sm, f32x4 acc[4][2]){
  float* tile = (float*)sm;
  const int tid = threadIdx.x, lane = tid & 63, wv = tid >> 6;
  const int wr = (wv >> 1) * 64, wc = (wv & 1) * 32;
  const int mm = lane & 15, quad = lane >> 4;
  #pragma unroll
  for (int tm = 0; tm < 4; tm++)
    #pragma unroll
    for (int tn = 0; tn < 2; tn++)
      #pragma unroll
      for (int i = 0; i < 4; i++)
        tile[(wr + tm*16 + quad*4 + i)*65 + wc + tn*16 + mm] = acc[tm][tn][i];
  __syncthreads();
}

// Coalesced epilogue over the 128x64 tile: 16-thread group per row, 8 rows
// per j-iter -> per row 16 lanes x 16B = 256B contiguous global traffic.
#define EPILOGUE2_FOR(rowvar, c4var) \
  const int tid = threadIdx.x; \
  const int g16 = tid >> 4; \
  const int c4var = (tid & 15) * 4; \
  for (int j = 0; j < 8; j++){ \
    const int rowvar = j*16 + g16;

// ---------------- W split / transpose-split ----------------
__global__ __launch_bounds__(256) void k_split(const float* __restrict__ W,
                                               ushort_t* __restrict__ Wah, ushort_t* __restrict__ Wal,
                                               ushort_t* __restrict__ Wbh, ushort_t* __restrict__ Wbl){
  __shared__ float t[32][33];
  const int i0 = blockIdx.y * 32, j0 = blockIdx.x * 32;
  const int r = threadIdx.x >> 3, c = (threadIdx.x & 7) * 4;
  const float4 v = *(const float4*)&W[(size_t)(i0 + r) * SDIM + j0 + c];
  float vv[4] = {v.x, v.y, v.z, v.w};
  ushort_t h[4], l[4];
  #pragma unroll
  for (int q = 0; q < 4; q++){ split2(vv[q], &h[q], &l[q]); t[r][c+q] = vv[q]; }
  *(ushort4*)&Wah[(size_t)(i0 + r) * SDIM + j0 + c] = make_ushort4(h[0],h[1],h[2],h[3]);
  *(ushort4*)&Wal[(size_t)(i0 + r) * SDIM + j0 + c] = make_ushort4(l[0],l[1],l[2],l[3]);
  __syncthreads();
  #pragma unroll
  for (int q = 0; q < 4; q++) split2(t[c+q][r], &h[q], &l[q]);
  *(ushort4*)&Wbh[(size_t)(j0 + r) * SDIM + i0 + c] = make_ushort4(h[0],h[1],h[2],h[3]);
  *(ushort4*)&Wbl[(size_t)(j0 + r) * SDIM + i0 + c] = make_ushort4(l[0],l[1],l[2],l[3]);
}

// XCD swizzles (bijective; nwg % 8 == 0 in both cases)
// 512 blocks: 16 m-tiles(128) x 32 n-tiles(64)
__device__ __forceinline__ void swzM2(int* m0, int* n0){
  const int b = blockIdx.x + (blockIdx.y << 5);
  const int xcd = b & 7, slot = b >> 3;          // slot 0..63
  *n0 = ((xcd << 2) + (slot >> 4)) << 6;
  *m0 = (slot & 15) << 7;
}
// 256 blocks: 8 m-tiles(128) x 32 n-tiles(64)
__device__ __forceinline__ void swzF2(int* m0, int* n0){
  const int b = blockIdx.x + (blockIdx.y << 5);
  const int xcd = b & 7, slot = b >> 3;          // slot 0..31
  *n0 = ((xcd << 2) + (slot >> 3)) << 6;
  *m0 = (slot & 7) << 7;
}

// M = W * W^T for Lanczos.
__global__ __launch_bounds__(256) void k_gemmM(const ushort_t* __restrict__ Wah, const ushort_t* __restrict__ Wal,
                                               float* __restrict__ Mmat){
  extern __shared__ __align__(16) ushort_t smem[];
  int m0, n0; swzM2(&m0, &n0);
  f32x4 acc[4][2] = {};
  gemm_core2<128,64>(smem, Wah, Wal, Wah, Wal, m0, n0, SDIM, acc);
  acc_to_tile2(smem, acc);
  const float* tile = (const float*)smem;
  EPILOGUE2_FOR(row, c4)
    f32x4 a = *(const f32x4*)&tile[row*65 + c4];
    *(f32x4*)&Mmat[(size_t)(m0 + row) * SDIM + n0 + c4] = a;
  }
}

// ---------------- Lanczos on M: one kernel per step ----------------
__global__ __launch_bounds__(256) void k_init(float* __restrict__ vRing,
                                              double* __restrict__ dotWV, double* __restrict__ dotWW,
                                              float* __restrict__ betaSq){
  __shared__ float red[256];
  int t = threadIdx.x;
  float vals[8];
  float s = 0.f;
  #pragma unroll
  for (int p = 0; p < 8; p++){
    int j = p*256 + t;
    unsigned h = (unsigned)j * 2654435761u;
    h ^= h >> 16; h *= 2246822519u; h ^= h >> 13;
    float r = (float)(h & 0xFFFFFFu) / 16777216.0f - 0.5f;
    vals[p] = r; s += r*r;
  }
  red[t] = s; __syncthreads();
  for (int o = 128; o > 0; o >>= 1){ if (t < o) red[t] += red[t+o]; __syncthreads(); }
  float inv = rsqrtf(red[0]);
  #pragma unroll
  for (int p = 0; p < 8; p++){
    int j = p*256 + t;
    vRing[SDIM + j] = vals[p]*inv;   // slot 1 = v_1
    vRing[j] = 0.f;                  // slot 0
    vRing[2*SDIM + j] = 0.f;         // slot 2
  }
  if (t < LM+2){ dotWV[t] = 0.0; dotWW[t] = 0.0; betaSq[t] = 0.f; }
}

__global__ __launch_bounds__(256) void k_lstep(const float* __restrict__ M,
    const float* __restrict__ wOld, float* __restrict__ wNew,
    float* __restrict__ vRing, double* __restrict__ dotWV, double* __restrict__ dotWW,
    float* __restrict__ betaSq, int s){
  __shared__ float vs[SDIM];
  __shared__ double pAl[4], pWw[4];
  const int tid = threadIdx.x, bid = blockIdx.x;
  if (s == 1){
    const float* v1 = vRing + SDIM;
    for (int j = tid; j < SDIM; j += 256) vs[j] = v1[j];
  } else {
    const double a  = dotWV[s-1];
    const double ww = dotWW[s-1];
    const float bpSq = betaSq[s-2];
    float bsq = (float)(ww - a*a - (double)bpSq);
    bsq = fmaxf(bsq, 1e-20f);
    const float beta = sqrtf(bsq), invb = 1.0f/beta;
    const float alpha = (float)a, bprev = sqrtf(bpSq);
    const float* vm1 = vRing + ((s-1)%3)*SDIM;
    const float* vm2 = vRing + ((s-2)%3)*SDIM;
    float* vdst = vRing + (s%3)*SDIM;
    for (int j = tid; j < SDIM; j += 256){
      float val = (wOld[j] - alpha*vm1[j] - bprev*vm2[j]) * invb;
      vs[j] = val;
      if (bid == 0) vdst[j] = val;
    }
    if (bid == 0 && tid == 0) betaSq[s-1] = bsq;
  }
  __syncthreads();
  const int wv = tid >> 6, lane = tid & 63;
  const int row = bid*4 + wv;
  const float4* Mr = (const float4*)(M + (size_t)row * SDIM);
  const float4* v4 = (const float4*)vs;
  float acc = 0.f;
  #pragma unroll
  for (int p = 0; p < 8; p++){
    int j4 = p*64 + lane;
    float4 m = Mr[j4], v = v4[j4];
    acc += m.x*v.x + m.y*v.y + m.z*v.z + m.w*v.w;
  }
  #pragma unroll
  for (int o = 32; o > 0; o >>= 1) acc += __shfl_down(acc, o);
  if (lane == 0){
    wNew[row] = acc;
    pAl[wv] = (double)acc * (double)vs[row];
    pWw[wv] = (double)acc * (double)acc;
  }
  __syncthreads();
  if (tid == 0){
    atomicAdd(&dotWV[s], pAl[0]+pAl[1]+pAl[2]+pAl[3]);
    atomicAdd(&dotWW[s], pWw[0]+pWw[1]+pWw[2]+pWw[3]);
  }
}

// lambda_max of tridiagonal via lane-parallel Sturm bisection (fp64)
__global__ void k_sturm(const double* __restrict__ dotWV, const float* __restrict__ betaSq,
                        const float* __restrict__ alphaIn, float* __restrict__ Lbuf){
  __shared__ double sa[LM+1], sb[LM+1];
  int lane = threadIdx.x;
  for (int i = lane; i <= LM; i += 64){
    if (i >= 1){
      sa[i] = dotWV[i];
      sb[i] = (i < LM) ? sqrt((double)betaSq[i]) : 0.0;
    }
  }
  __syncthreads();
  double phi = -1e300, plo = 1e300;
  for (int i = 1 + lane; i <= LM; i += 64){
    double r = (i > 1 ? sb[i-1] : 0.0) + (i < LM ? sb[i] : 0.0);
    phi = fmax(phi, sa[i] + r);
    plo = fmin(plo, sa[i] - r);
  }
  for (int o = 32; o > 0; o >>= 1){
    phi = fmax(phi, __shfl_down(phi, o));
    plo = fmin(plo, __shfl_down(plo, o));
  }
  double hi = __shfl(phi, 0), lo = __shfl(plo, 0);
  for (int round = 0; round < 6; round++){
    double x = lo + (hi - lo) * (double)(lane + 1) / 65.0;
    int cnt = 0;
    double dd = sa[1] - x;
    if (dd < 0) cnt++;
    for (int i = 2; i <= LM; i++){
      double off = sb[i-1];
      if (fabs(dd) < 1e-300) dd = -1e-300;
      dd = sa[i] - x - off*off/dd;
      if (dd < 0) cnt++;
    }
    unsigned long long bal = __ballot(cnt == LM);
    int p = (bal == 0ull) ? 64 : (__ffsll((unsigned long long)bal) - 1);
    double newhi = (p <= 63) ? lo + (hi - lo) * (double)(p + 1) / 65.0 : hi;
    double newlo = (p >= 1)  ? lo + (hi - lo) * (double)p / 65.0       : lo;
    hi = newhi; lo = newlo;
  }
  if (lane == 0){
    double L = 0.5*(lo + hi);
    Lbuf[0] = (float)(1.0 / L);
    Lbuf[1] = (float)(0.5 * (double)alphaIn[0] / L);
  }
}

// ---------------- FISTA ----------------

__global__ __launch_bounds__(256) void k_A0(const float* __restrict__ Y, const float* __restrict__ src,
                                            float* __restrict__ yd, ushort_t* __restrict__ sresh,
                                            ushort_t* __restrict__ sresl, float* __restrict__ out,
                                            const float* __restrict__ Lbuf){
  int idx = blockIdx.x*256 + threadIdx.x;
  float invL = Lbuf[0], th = Lbuf[1];
  float y = Y[idx], s = src[idx];
  split2(s*y, &sresh[idx], &sresl[idx]);
  float xn = softt(y*invL, th);
  int b = idx >> 11, i = idx & 2047;
  out[(size_t)b*4096 + 2048 + i] = xn;
  yd[idx] = xn;   // c0 = 0 -> y1 = x1
}

// GEMM1: acc[b][i] = sum_k ym[b][k]*W[i][k]; fused res/sres/delta update
__global__ __launch_bounds__(256) void k_gemmA(
    const ushort_t* __restrict__ Wah, const ushort_t* __restrict__ Wal,
    const ushort_t* __restrict__ ymh, const ushort_t* __restrict__ yml,
    const float* __restrict__ Y, const float* __restrict__ src,
    float* __restrict__ yd, float* __restrict__ out,
    ushort_t* __restrict__ sresh, ushort_t* __restrict__ sresl,
    const float* __restrict__ Lbuf, float ck)
{
  extern __shared__ __align__(16) ushort_t smem[];
  f32x4 acc[4][2] = {};
  int m0, n0; swzF2(&m0, &n0);
  gemm_core2<128,64>(smem, ymh, yml, Wah, Wal, m0, n0, SDIM, acc);
  acc_to_tile2(smem, acc);
  const float* tile = (const float*)smem;
  const float invL = Lbuf[0], th = Lbuf[1];
  EPILOGUE2_FOR(row, c4)
    const int brow = m0 + row;
    const size_t g  = (size_t)brow*SDIM + n0 + c4;
    const size_t go = (size_t)brow*4096 + 2048 + n0 + c4;
    f32x4 a   = *(const f32x4*)&tile[row*65 + c4];
    f32x4 s4  = *(const f32x4*)&src[g];
    f32x4 y4  = *(const f32x4*)&Y[g];
    f32x4 yd4 = *(const f32x4*)&yd[g];
    f32x4 xo4 = *(const f32x4*)&out[go];
    f32x4 res, xn, yn;
    ushort4 sh, sl;
    #pragma unroll
    for (int q = 0; q < 4; q++){
      res[q] = y4[q] - s4[q]*a[q] - yd4[q];
      xn[q]  = softt(yd4[q] + res[q]*invL, th);
      yn[q]  = xn[q] + ck*(xn[q] - xo4[q]);
    }
    split2(s4[0]*res[0], &sh.x, &sl.x);
    split2(s4[1]*res[1], &sh.y, &sl.y);
    split2(s4[2]*res[2], &sh.z, &sl.z);
    split2(s4[3]*res[3], &sh.w, &sl.w);
    *(ushort4*)&sresh[g] = sh;
    *(ushort4*)&sresl[g] = sl;
    *(f32x4*)&out[go] = xn;
    *(f32x4*)&yd[g]   = yn;
  }
}

// GEMM2: acc[b][j] = sum_i sres[b][i]*W[i][j]; fused theta update
template<bool FIRST>
__global__ __launch_bounds__(256) void k_gemmB(
    const ushort_t* __restrict__ Wbh, const ushort_t* __restrict__ Wbl,
    const ushort_t* __restrict__ sresh, const ushort_t* __restrict__ sresl,
    ushort_t* __restrict__ ymh, ushort_t* __restrict__ yml,
    float* __restrict__ out, const float* __restrict__ Lbuf, float ck)
{
  extern __shared__ __align__(16) ushort_t smem[];
  f32x4 acc[4][2] = {};
  int m0, n0; swzF2(&m0, &n0);
  gemm_core2<128,64>(smem, sresh, sresl, Wbh, Wbl, m0, n0, SDIM, acc);
  acc_to_tile2(smem, acc);
  const float* tile = (const float*)smem;
  const float invL = Lbuf[0], th = Lbuf[1];
  EPILOGUE2_FOR(row, c4)
    const int brow = m0 + row;
    const size_t g  = (size_t)brow*SDIM + n0 + c4;
    const size_t go = (size_t)brow*4096 + n0 + c4;
    f32x4 a = *(const f32x4*)&tile[row*65 + c4];
    f32x4 ym4, xo4;
    if (FIRST){
      ym4 = (f32x4){0.f,0.f,0.f,0.f};
      xo4 = (f32x4){0.f,0.f,0.f,0.f};
    } else {
      ushort4 h4 = *(const ushort4*)&ymh[g];
      ushort4 l4 = *(const ushort4*)&yml[g];
      ym4[0] = bf2f(h4.x) + bf2f(l4.x);
      ym4[1] = bf2f(h4.y) + bf2f(l4.y);
      ym4[2] = bf2f(h4.z) + bf2f(l4.z);
      ym4[3] = bf2f(h4.w) + bf2f(l4.w);
      xo4 = *(const f32x4*)&out[go];
    }
    f32x4 xn, yn;
    ushort4 hh, ll;
    #pragma unroll
    for (int q = 0; q < 4; q++){
      xn[q] = softt(ym4[q] + a[q]*invL, th);
      yn[q] = xn[q] + ck*(xn[q] - xo4[q]);
    }
    split2(yn[0], &hh.x, &ll.x);
    split2(yn[1], &hh.y, &ll.y);
    split2(yn[2], &hh.z, &ll.z);
    split2(yn[3], &hh.w, &ll.w);
    *(f32x4*)&out[go] = xn;
    *(ushort4*)&ymh[g] = hh;
    *(ushort4*)&yml[g] = ll;
  }
}

// ---------------- host ----------------

extern "C" void kernel_launch(void* const* d_in, const int* in_sizes, int n_in,
                              void* d_out, int out_size, void* d_ws, size_t ws_size,
                              hipStream_t stream) {
  const float* src   = (const float*)d_in[0];
  const float* Y     = (const float*)d_in[1];
  const float* W     = (const float*)d_in[2];
  const float* alpha = (const float*)d_in[3];
  float* out = (float*)d_out;
  float* ws  = (float*)d_ws;

  const size_t M1 = 1024*1024;
  float* Mmat = ws;                      // 4M floats (16MB)
  float* yd   = ws + 4*M1;               // 2M floats
  float* lanc = ws + 6*M1;
  float* w0      = lanc;                 // 2048
  float* w1      = lanc + SDIM;          // 2048
  float* vRing   = lanc + 2*SDIM;        // 3*2048
  double* dotWV  = (double*)(lanc + 5*SDIM);        // 128 doubles
  double* dotWW  = dotWV + 128;                     // 128 doubles
  float* betaSq  = lanc + 5*SDIM + 512;             // 128 floats
  float* Lbuf    = betaSq + 128;                    // 2
  ushort_t* u16 = (ushort_t*)(ws + 7*M1);
  ushort_t* Wah = u16;                   // 4M u16 each
  ushort_t* Wal = u16 + 4*M1;
  ushort_t* Wbh = u16 + 8*M1;
  ushort_t* Wbl = u16 + 12*M1;
  ushort_t* ymh = u16 + 16*M1;           // 2M u16 each
  ushort_t* yml = u16 + 18*M1;
  ushort_t* sresh = u16 + 20*M1;
  ushort_t* sresl = u16 + 22*M1;

  const size_t LDSB = 98304;   // 2 x 48KB double-buffered stage

  // ---- split W (and W^T) into bf16 hi/lo ----
  k_split<<<dim3(64,64), 256, 0, stream>>>(W, Wah, Wal, Wbh, Wbl);
  // ---- M = W W^T for Lanczos ----
  k_gemmM<<<dim3(32,16), 256, LDSB, stream>>>(Wah, Wal, Mmat);

  // ---- Lanczos for L = lambda_max: one kernel per step ----
  float* wb[2] = { w0, w1 };
  k_init<<<1, 256, 0, stream>>>(vRing, dotWV, dotWW, betaSq);
  for (int s = 1; s <= LM; s++){
    k_lstep<<<512, 256, 0, stream>>>(Mmat, wb[(s+1)&1], wb[s&1], vRing, dotWV, dotWW, betaSq, s);
  }
  k_sturm<<<1, 64, 0, stream>>>(dotWV, betaSq, alpha, Lbuf);

  // ---- momentum coefficients (data independent) ----
  double t = 1.0;
  float ckv[NITER];
  for (int k = 0; k < NITER; k++){
    double tn = 0.5*(1.0 + sqrt(1.0 + 4.0*t*t));
    ckv[k] = (float)((t - 1.0)/tn);
    t = tn;
  }

  // ---- FISTA ----
  k_A0<<<(BATCH*SDIM)/256, 256, 0, stream>>>(Y, src, yd, sresh, sresl, out, Lbuf);
  k_gemmB<true><<<dim3(32,8), 256, LDSB, stream>>>(Wbh, Wbl, sresh, sresl, ymh, yml, out, Lbuf, ckv[0]);
  for (int k = 1; k < NITER; k++){
    k_gemmA<<<dim3(32,8), 256, LDSB, stream>>>(Wah, Wal, ymh, yml, Y, src, yd, out, sresh, sresl, Lbuf, ckv[k]);
    k_gemmB<false><<<dim3(32,8), 256, LDSB, stream>>>(Wbh, Wbl, sresh, sresl, ymh, yml, out, Lbuf, ckv[k]);
  }
  (void)in_sizes; (void)n_in; (void)out_size; (void)ws_size;
}